// Round 7
// baseline (308.469 us; speedup 1.0000x reference)
//
#include <hip/hip_runtime.h>

// HybridQLSTMQuantum, MI355X — v7: two-dispatch split (GEMM -> ws, then
// wave-parallel recurrence), with v6 single-kernel fallback if ws too small.
//
// qgate identity (verified analytically):
//   qgate(angles)[w] = prod_{j<=w} cos(angles[j])
//
// K1 (qlstm_gemm): A[b][t][o] = x[t,b,:].Wg[w,:256], all 65536 rows -> d_ws.
//   Grid 1024 x 256 (4 waves; wave = k-slice, W slice register-resident,
//   R6-proven spill-free). X loads uniform-broadcast per half-wave.
//   Partials reduced via LDS. ~4 blocks/CU -> real TLP.
// K2 (qlstm_rec): grid 32 x 64. Lane = (b_sub, w): 8 lanes per batch row,
//   8 rows per wave. All 4 gates of wire w live IN-LANE -> no gate-gather
//   on the serial chain. Cross-lane per step: 8 h-broadcast ds_swizzles +
//   3 DPP rounds x 4 gates (cumprod). A prefetched 2 steps ahead into
//   named registers (no runtime-indexed arrays).
// Runtime dtype sniff retained. All parameter loads sanitized.

#define S_LEN 256
#define BATCH 256
#define DIMK  256
#define FAN   264
#define NROWS (S_LEN * BATCH)
#define WS_NEED ((size_t)NROWS * 32 * 4)

__device__ __forceinline__ float lo16f(unsigned u) {
    union { unsigned u; float f; } v; v.u = u << 16; return v.f;
}
__device__ __forceinline__ float hi16f(unsigned u) {
    union { unsigned u; float f; } v; v.u = u & 0xffff0000u; return v.f;
}
__device__ __forceinline__ float b2f(unsigned short u) {
    union { unsigned u; float f; } v; v.u = ((unsigned)u) << 16; return v.f;
}
__device__ __forceinline__ unsigned short f2b(float f) {
    union { float f; unsigned u; } v; v.f = f;
    unsigned r = v.u + 0x7fffu + ((v.u >> 16) & 1u);  // RNE
    return (unsigned short)(r >> 16);
}
__device__ __forceinline__ float sane(float x) {
    return (__builtin_fabsf(x) < 1e30f) ? x : 0.f;   // NaN compares false -> 0
}
__device__ __forceinline__ float ldE(const void* p, int idx, bool f32) {
    return f32 ? ((const float*)p)[idx] : b2f(((const unsigned short*)p)[idx]);
}
__device__ __forceinline__ void stE(void* p, long idx, float v, bool f32) {
    if (f32) ((float*)p)[idx] = v;
    else     ((unsigned short*)p)[idx] = f2b(v);
}
__device__ __forceinline__ float sigm(float x) {
    return 1.f - __fdividef(1.f, __expf(x) + 1.f);
}
__device__ __forceinline__ float tanh_f(float x) {
    return 1.f - __fdividef(2.f, __expf(2.f * x) + 1.f);
}

// DPP row_shr:K within 16-lane rows (CTRL = 0x110|K); invalid lanes keep old.
template<int CTRL>
__device__ __forceinline__ float dpp_f(float x) {
    int xi = __builtin_bit_cast(int, x);
    int r = __builtin_amdgcn_update_dpp(xi, xi, CTRL, 0xF, 0xF, false);
    return __builtin_bit_cast(float, r);
}
// ds_swizzle BitMode: src_lane = ((lane & and) | or) ^ xor, imm = xor<<10|or<<5|and
template<int IMM>
__device__ __forceinline__ float swz_f(float x) {
    return __builtin_bit_cast(float,
        __builtin_amdgcn_ds_swizzle(__builtin_bit_cast(int, x), IMM));
}
__device__ __forceinline__ float rdlane_f(float x, int l) {
    return __builtin_bit_cast(float,
        __builtin_amdgcn_readlane(__builtin_bit_cast(int, x), l));
}

__device__ __forceinline__ int sniff_f32(const void* X) {
    const unsigned short* u = (const unsigned short*)X;
    int hits = 0;
    for (int i = 0; i < 64; ++i) {
        int e = (u[2 * i] >> 7) & 0xFF;
        if (e >= 110 && e <= 135) ++hits;
    }
    return (hits < 32) ? 1 : 0;
}

// ============================ K1: GEMM -> ws ============================
__global__ __launch_bounds__(256, 4) void qlstm_gemm(
    const void* __restrict__ X,
    const void* __restrict__ Wf, const void* __restrict__ Wi,
    const void* __restrict__ Wu, const void* __restrict__ Wo,
    float* __restrict__ A)
{
    __shared__ float red[4][64][32];   // 32 KiB k-partials
    __shared__ int s_isf32;

    const int tid = threadIdx.x;
    if (tid == 0) s_isf32 = sniff_f32(X);
    __syncthreads();
    const bool f32 = (s_isf32 != 0);

    const int kv = tid >> 6;        // wave = k-slice (0..3)
    const int l  = tid & 63;
    const int o  = l & 31;
    const int th = l >> 5;          // row-half
    const int g  = o >> 3, w = o & 7;
    const void* Wg = (g == 0) ? Wf : (g == 1) ? Wi : (g == 2) ? Wu : Wo;

    // persistent W slice in registers, unified f32 storage (R6-proven)
    float4 wreg[16];
    if (f32) {
        const float4* wr = (const float4*)((const float*)Wg + w * FAN + kv * 64);
#pragma unroll
        for (int i = 0; i < 16; ++i) wreg[i] = wr[i];
    } else {
        const uint4* wr = (const uint4*)((const unsigned short*)Wg + w * FAN + kv * 64);
#pragma unroll
        for (int i = 0; i < 8; ++i) {
            uint4 wu = wr[i];
            wreg[2 * i + 0] = make_float4(lo16f(wu.x), hi16f(wu.x),
                                          lo16f(wu.y), hi16f(wu.y));
            wreg[2 * i + 1] = make_float4(lo16f(wu.z), hi16f(wu.z),
                                          lo16f(wu.w), hi16f(wu.w));
        }
    }

    const long rowbase = (long)blockIdx.x * 64;   // rows = b*256 + t
    for (int j = 0; j < 32; ++j) {
        const int rl = th * 32 + j;
        const long row = rowbase + rl;
        const int t = (int)(row & 255), bb = (int)(row >> 8);
        float a0 = 0.f, a1 = 0.f, a2 = 0.f, a3 = 0.f;
        if (f32) {
            const float4* xr = (const float4*)((const float*)X
                    + ((long)t * BATCH + bb) * DIMK + kv * 64);
#pragma unroll
            for (int i = 0; i < 16; ++i) {
                float4 xu = xr[i];
                a0 = fmaf(xu.x, wreg[i].x, a0);
                a1 = fmaf(xu.y, wreg[i].y, a1);
                a2 = fmaf(xu.z, wreg[i].z, a2);
                a3 = fmaf(xu.w, wreg[i].w, a3);
            }
        } else {
            const uint4* xr = (const uint4*)((const unsigned short*)X
                    + ((long)t * BATCH + bb) * DIMK + kv * 64);
#pragma unroll
            for (int i = 0; i < 8; ++i) {
                uint4 xu = xr[i];
                a0 = fmaf(lo16f(xu.x), wreg[2 * i].x, a0);
                a1 = fmaf(hi16f(xu.x), wreg[2 * i].y, a1);
                a2 = fmaf(lo16f(xu.y), wreg[2 * i].z, a2);
                a3 = fmaf(hi16f(xu.y), wreg[2 * i].w, a3);
                a0 = fmaf(lo16f(xu.z), wreg[2 * i + 1].x, a0);
                a1 = fmaf(hi16f(xu.z), wreg[2 * i + 1].y, a1);
                a2 = fmaf(lo16f(xu.w), wreg[2 * i + 1].z, a2);
                a3 = fmaf(hi16f(xu.w), wreg[2 * i + 1].w, a3);
            }
        }
        red[kv][rl][o] = (a0 + a1) + (a2 + a3);
    }
    __syncthreads();
    for (int idx = tid; idx < 64 * 32; idx += 256) {
        const int rl = idx >> 5, oo = idx & 31;
        float s = red[0][rl][oo] + red[1][rl][oo]
                + red[2][rl][oo] + red[3][rl][oo];
        A[(rowbase + rl) * 32 + oo] = sane(s);
    }
}

// ========================= K2: recurrence =========================
__global__ __launch_bounds__(64) void qlstm_rec(
    const void* __restrict__ X,  const void* __restrict__ hx, const void* __restrict__ cx,
    const void* __restrict__ Wf, const void* __restrict__ bf_,
    const void* __restrict__ Wi, const void* __restrict__ bi_,
    const void* __restrict__ Wu, const void* __restrict__ bu_,
    const void* __restrict__ Wo, const void* __restrict__ bo_,
    const void* __restrict__ tf, const void* __restrict__ ti,
    const void* __restrict__ tu, const void* __restrict__ to_,
    void* __restrict__ out, const float* __restrict__ A)
{
    __shared__ int s_isf32;
    const int tid = threadIdx.x;
    if (tid == 0) s_isf32 = sniff_f32(X);
    __syncthreads();
    const bool f32 = (s_isf32 != 0);

    const int w     = tid & 7;          // wire
    const int bglob = blockIdx.x * 8 + (tid >> 3);

    const void* Wg_[4] = { Wf, Wi, Wu, Wo };
    const void* bg_[4] = { bf_, bi_, bu_, bo_ };
    const void* tg_[4] = { tf, ti, tu, to_ };

    float Wh[4][8], bt[4];
#pragma unroll
    for (int g = 0; g < 4; ++g) {
#pragma unroll
        for (int j = 0; j < 8; ++j)
            Wh[g][j] = sane(ldE(Wg_[g], w * FAN + DIMK + j, f32));
        bt[g] = sane(ldE(bg_[g], w, f32)) + sane(ldE(tg_[g], w, f32));
    }
    float h = sane(ldE(hx, bglob * 8 + w, f32));
    float c = sane(ldE(cx, bglob * 8 + w, f32));

    // inclusive cumprod over the 8-lane wire group via DPP row_shr
    auto cumprod8 = [&](float e) {
        { float v = dpp_f<0x111>(e); e = (w >= 1) ? e * v : e; }
        { float v = dpp_f<0x112>(e); e = (w >= 2) ? e * v : e; }
        { float v = dpp_f<0x114>(e); e = (w >= 4) ? e * v : e; }
        return e;
    };

    auto ldA = [&](int t, int g) {
        return A[(((long)bglob << 8) | t) * 32 + g * 8 + w];
    };

    auto STEP = [&](int t, float aF, float aI, float aU, float aO) {
        // broadcast the 8 h's of this b across its 8-lane group
        // src = (lane & 0x38) | j  ->  imm = (j<<5) | 0x38
        float hj[8];
        hj[0] = swz_f<0x038>(h); hj[1] = swz_f<0x058>(h);
        hj[2] = swz_f<0x078>(h); hj[3] = swz_f<0x098>(h);
        hj[4] = swz_f<0x0B8>(h); hj[5] = swz_f<0x0D8>(h);
        hj[6] = swz_f<0x0F8>(h); hj[7] = swz_f<0x118>(h);
        float angF = aF + bt[0], angI = aI + bt[1];
        float angU = aU + bt[2], angO = aO + bt[3];
#pragma unroll
        for (int j = 0; j < 8; ++j) {
            angF = fmaf(hj[j], Wh[0][j], angF);
            angI = fmaf(hj[j], Wh[1][j], angI);
            angU = fmaf(hj[j], Wh[2][j], angU);
            angO = fmaf(hj[j], Wh[3][j], angO);
        }
        float Ef = cumprod8(__cosf(angF));
        float Ei = cumprod8(__cosf(angI));
        float Eu = cumprod8(__cosf(angU));
        float Eo = cumprod8(__cosf(angO));
        float vf = sigm(Ef), vi = sigm(Ei), vu = tanh_f(Eu), vo = sigm(Eo);
        c = fmaf(vf, c, vi * vu);
        h = vo * tanh_f(c);
        stE(out, (long)t * 2048 + bglob * 8 + w, h, f32);
    };

    // 2-deep A prefetch into NAMED registers (static indexing only)
    float aF0 = ldA(0, 0), aI0 = ldA(0, 1), aU0 = ldA(0, 2), aO0 = ldA(0, 3);
    float aF1 = ldA(1, 0), aI1 = ldA(1, 1), aU1 = ldA(1, 2), aO1 = ldA(1, 3);
    for (int t = 0; t < S_LEN; t += 2) {
        const int tp2 = (t + 2 < S_LEN) ? t + 2 : S_LEN - 1;
        const int tp3 = (t + 3 < S_LEN) ? t + 3 : S_LEN - 1;
        float nF0 = ldA(tp2, 0), nI0 = ldA(tp2, 1);
        float nU0 = ldA(tp2, 2), nO0 = ldA(tp2, 3);
        STEP(t, aF0, aI0, aU0, aO0);
        float nF1 = ldA(tp3, 0), nI1 = ldA(tp3, 1);
        float nU1 = ldA(tp3, 2), nO1 = ldA(tp3, 3);
        STEP(t + 1, aF1, aI1, aU1, aO1);
        aF0 = nF0; aI0 = nI0; aU0 = nU0; aO0 = nO0;
        aF1 = nF1; aI1 = nI1; aU1 = nU1; aO1 = nO1;
    }
    stE(out, 524288L + bglob * 8 + w, h, f32);   // hT
    stE(out, 526336L + bglob * 8 + w, c, f32);   // cT
}

// ================= v6 fallback (ws too small): proven at 140us =================
__global__ __launch_bounds__(320, 1) void qlstm_fused_v6(
    const void* __restrict__ X,  const void* __restrict__ hx, const void* __restrict__ cx,
    const void* __restrict__ Wf, const void* __restrict__ bf_,
    const void* __restrict__ Wi, const void* __restrict__ bi_,
    const void* __restrict__ Wu, const void* __restrict__ bu_,
    const void* __restrict__ Wo, const void* __restrict__ bo_,
    const void* __restrict__ tf, const void* __restrict__ ti,
    const void* __restrict__ tu, const void* __restrict__ to_,
    void* __restrict__ out)
{
    __shared__ float As4[2][4][32][32];
    __shared__ int s_isf32;

    const int tid = threadIdx.x;
    const int b   = blockIdx.x;

    if (tid == 0) s_isf32 = sniff_f32(X);
    __syncthreads();
    const bool f32 = (s_isf32 != 0);

    const int wv   = tid >> 6;
    const int lane = tid & 63;
    const int kv   = wv - 1;
    const int o    = lane & 31;
    const int th   = lane >> 5;
    const int g    = o >> 3, w = o & 7;
    const void* Wg = (g == 0) ? Wf : (g == 1) ? Wi : (g == 2) ? Wu : Wo;

    float4 wreg[16];
    if (wv >= 1) {
        if (f32) {
            const float4* wr = (const float4*)((const float*)Wg + w * FAN + kv * 64);
#pragma unroll
            for (int i = 0; i < 16; ++i) wreg[i] = wr[i];
        } else {
            const uint4* wr = (const uint4*)((const unsigned short*)Wg + w * FAN + kv * 64);
#pragma unroll
            for (int i = 0; i < 8; ++i) {
                uint4 wu = wr[i];
                wreg[2 * i + 0] = make_float4(lo16f(wu.x), hi16f(wu.x),
                                              lo16f(wu.y), hi16f(wu.y));
                wreg[2 * i + 1] = make_float4(lo16f(wu.z), hi16f(wu.z),
                                              lo16f(wu.w), hi16f(wu.w));
            }
        }
    }

    auto fill = [&](int ch) {
        float (*dst)[32] = As4[ch & 1][kv];
        const int tb = ch * 32 + th * 16;
        if (f32) {
            for (int j = 0; j < 16; ++j) {
                const float4* xr = (const float4*)((const float*)X
                        + ((long)(tb + j) * BATCH + b) * DIMK + kv * 64);
                float a0 = 0.f, a1 = 0.f, a2 = 0.f, a3 = 0.f;
#pragma unroll
                for (int i = 0; i < 16; ++i) {
                    float4 xu = xr[i];
                    a0 = fmaf(xu.x, wreg[i].x, a0);
                    a1 = fmaf(xu.y, wreg[i].y, a1);
                    a2 = fmaf(xu.z, wreg[i].z, a2);
                    a3 = fmaf(xu.w, wreg[i].w, a3);
                }
                dst[th * 16 + j][o] = sane((a0 + a1) + (a2 + a3));
            }
        } else {
            for (int j = 0; j < 16; ++j) {
                const uint4* xr = (const uint4*)((const unsigned short*)X
                        + ((long)(tb + j) * BATCH + b) * DIMK + kv * 64);
                float a0 = 0.f, a1 = 0.f, a2 = 0.f, a3 = 0.f;
#pragma unroll
                for (int i = 0; i < 8; ++i) {
                    uint4 xu = xr[i];
                    a0 = fmaf(lo16f(xu.x), wreg[2 * i].x, a0);
                    a1 = fmaf(hi16f(xu.x), wreg[2 * i].y, a1);
                    a2 = fmaf(lo16f(xu.y), wreg[2 * i].z, a2);
                    a3 = fmaf(hi16f(xu.y), wreg[2 * i].w, a3);
                    a0 = fmaf(lo16f(xu.z), wreg[2 * i + 1].x, a0);
                    a1 = fmaf(hi16f(xu.z), wreg[2 * i + 1].y, a1);
                    a2 = fmaf(lo16f(xu.w), wreg[2 * i + 1].z, a2);
                    a3 = fmaf(hi16f(xu.w), wreg[2 * i + 1].w, a3);
                }
                dst[th * 16 + j][o] = sane((a0 + a1) + (a2 + a3));
            }
        }
    };

    float Wh[8];
    float bt = 0.f, h = 0.f, c = 0.f, qv = 1.f;
    int rw = 0, rg = 0;
    if (tid < 32) {
        rw = tid & 7; rg = tid >> 3;
        const void* bg = (rg == 0) ? bf_ : (rg == 1) ? bi_ : (rg == 2) ? bu_ : bo_;
        const void* tg = (rg == 0) ? tf  : (rg == 1) ? ti  : (rg == 2) ? tu  : to_;
        const int wr = rw * FAN;
#pragma unroll
        for (int j = 0; j < 8; ++j)
            Wh[j] = sane(ldE(Wg, wr + DIMK + j, f32));
        bt = sane(ldE(bg, rw, f32)) + sane(ldE(tg, rw, f32));
        h  = sane(ldE(hx, b * 8 + rw, f32));
        c  = sane(ldE(cx, b * 8 + rw, f32));
        qv = (rg == 2) ? 2.f : 1.f;
    }
    if (wv == 0) __builtin_amdgcn_s_setprio(1);

    if (wv >= 1) fill(0);
    __syncthreads();

    for (int ch = 0; ch < 8; ++ch) {
        if (wv >= 1 && ch + 1 < 8) fill(ch + 1);
        if (tid < 32) {
            const int buf = ch & 1;
            float n0 = As4[buf][0][0][tid], n1 = As4[buf][1][0][tid];
            float n2 = As4[buf][2][0][tid], n3 = As4[buf][3][0][tid];
            float a_cur = (n0 + n1) + (n2 + n3);
            for (int s = 0; s < 32; ++s) {
                const int sn = (s < 31) ? s + 1 : s;
                float m0 = As4[buf][0][sn][tid], m1 = As4[buf][1][sn][tid];
                float m2 = As4[buf][2][sn][tid], m3 = As4[buf][3][sn][tid];
                float d0 = 0.f, d1 = 0.f;
#pragma unroll
                for (int j = 0; j < 8; j += 2) {
                    d0 = fmaf(rdlane_f(h, j),     Wh[j],     d0);
                    d1 = fmaf(rdlane_f(h, j + 1), Wh[j + 1], d1);
                }
                float ang = a_cur + bt + (d0 + d1);
                float e = __cosf(ang);
                { float v = dpp_f<0x111>(e); e = (rw >= 1) ? e * v : e; }
                { float v = dpp_f<0x112>(e); e = (rw >= 2) ? e * v : e; }
                { float v = dpp_f<0x114>(e); e = (rw >= 4) ? e * v : e; }
                float ez  = __expf(qv * e);
                float val = 1.f - __fdividef(qv, ez + 1.f);
                float fg = swz_f<0x007>(val);
                float ig = swz_f<0x107>(val);
                float ug = swz_f<0x207>(val);
                float og = swz_f<0x307>(val);
                c = fmaf(fg, c, ig * ug);
                float e2 = __expf(2.f * c);
                float th2 = 1.f - __fdividef(2.f, e2 + 1.f);
                h = og * th2;
                if (rg == 0)
                    stE(out, (long)(ch * 32 + s) * 2048 + b * 8 + rw, h, f32);
                a_cur = (m0 + m1) + (m2 + m3);
            }
        }
        __syncthreads();
    }

    if (tid < 32 && rg == 0) {
        stE(out, 524288L + b * 8 + rw, h, f32);
        stE(out, 526336L + b * 8 + rw, c, f32);
    }
}

extern "C" void kernel_launch(void* const* d_in, const int* in_sizes, int n_in,
                              void* d_out, int out_size, void* d_ws, size_t ws_size,
                              hipStream_t stream) {
    if (d_ws != nullptr && ws_size >= WS_NEED) {
        qlstm_gemm<<<dim3(NROWS / 64), dim3(256), 0, stream>>>(
            d_in[0], d_in[3], d_in[5], d_in[7], d_in[9], (float*)d_ws);
        qlstm_rec<<<dim3(BATCH / 8), dim3(64), 0, stream>>>(
            d_in[0], d_in[1], d_in[2],
            d_in[3], d_in[4], d_in[5], d_in[6],
            d_in[7], d_in[8], d_in[9], d_in[10],
            d_in[11], d_in[12], d_in[13], d_in[14],
            d_out, (const float*)d_ws);
    } else {
        qlstm_fused_v6<<<dim3(BATCH), dim3(320), 0, stream>>>(
            d_in[0], d_in[1], d_in[2],
            d_in[3], d_in[4], d_in[5], d_in[6],
            d_in[7], d_in[8], d_in[9], d_in[10],
            d_in[11], d_in[12], d_in[13], d_in[14],
            d_out);
    }
}

// Round 8
// 307.169 us; speedup vs baseline: 1.0042x; 1.0042x over previous
//
#include <hip/hip_runtime.h>

// HybridQLSTMQuantum, MI355X — v8: two-dispatch split.
//   K1: spill-free GEMM (launch_bounds(256,2) lifts R7's 128-VGPR cap).
//   K2: recurrence with DPP-only cross-lane (no LDS pipe in the serial chain).
//
// qgate identity (verified analytically):
//   qgate(angles)[w] = prod_{j<=w} cos(angles[j])
//
// K2 layout: 64 blocks x 64 thr; wave = 4 batch rows x 16 lanes.
//   lane p = w(0..7) x dup(0..1); dup half computes redundantly so the
//   16-lane row holds h with period 8 (consistent by induction).
//   h all-to-all via XOR-basis DPP: quad_perm 0xB1 (xor1), 0x4E (xor2),
//   row_half_mirror 0x141 (xor7); compositions give xor3..6. Lane w's
//   coefficient for h_{w^m} is Whm[g][m] = Wh_g[w][w^m] (pre-permuted).
//   Cumprod via DPP row_shr (proven). Zero LDS ops in the chain.
// v6 single-kernel fallback retained for small ws.

#define S_LEN 256
#define BATCH 256
#define DIMK  256
#define FAN   264
#define NROWS (S_LEN * BATCH)
#define WS_NEED ((size_t)NROWS * 32 * 4)

__device__ __forceinline__ float lo16f(unsigned u) {
    union { unsigned u; float f; } v; v.u = u << 16; return v.f;
}
__device__ __forceinline__ float hi16f(unsigned u) {
    union { unsigned u; float f; } v; v.u = u & 0xffff0000u; return v.f;
}
__device__ __forceinline__ float b2f(unsigned short u) {
    union { unsigned u; float f; } v; v.u = ((unsigned)u) << 16; return v.f;
}
__device__ __forceinline__ unsigned short f2b(float f) {
    union { float f; unsigned u; } v; v.f = f;
    unsigned r = v.u + 0x7fffu + ((v.u >> 16) & 1u);  // RNE
    return (unsigned short)(r >> 16);
}
__device__ __forceinline__ float sane(float x) {
    return (__builtin_fabsf(x) < 1e30f) ? x : 0.f;   // NaN compares false -> 0
}
__device__ __forceinline__ float ldE(const void* p, int idx, bool f32) {
    return f32 ? ((const float*)p)[idx] : b2f(((const unsigned short*)p)[idx]);
}
__device__ __forceinline__ void stE(void* p, long idx, float v, bool f32) {
    if (f32) ((float*)p)[idx] = v;
    else     ((unsigned short*)p)[idx] = f2b(v);
}
__device__ __forceinline__ float sigm(float x) {
    return 1.f - __fdividef(1.f, __expf(x) + 1.f);
}
__device__ __forceinline__ float tanh_f(float x) {
    return 1.f - __fdividef(2.f, __expf(2.f * x) + 1.f);
}

// DPP: 0x000-0xFF quad_perm; 0x110|K row_shr:K; 0x141 row_half_mirror.
template<int CTRL>
__device__ __forceinline__ float dpp_f(float x) {
    int xi = __builtin_bit_cast(int, x);
    int r = __builtin_amdgcn_update_dpp(xi, xi, CTRL, 0xF, 0xF, false);
    return __builtin_bit_cast(float, r);
}
template<int IMM>
__device__ __forceinline__ float swz_f(float x) {
    return __builtin_bit_cast(float,
        __builtin_amdgcn_ds_swizzle(__builtin_bit_cast(int, x), IMM));
}
__device__ __forceinline__ float rdlane_f(float x, int l) {
    return __builtin_bit_cast(float,
        __builtin_amdgcn_readlane(__builtin_bit_cast(int, x), l));
}

__device__ __forceinline__ int sniff_f32(const void* X) {
    const unsigned short* u = (const unsigned short*)X;
    int hits = 0;
    for (int i = 0; i < 64; ++i) {
        int e = (u[2 * i] >> 7) & 0xFF;
        if (e >= 110 && e <= 135) ++hits;
    }
    return (hits < 32) ? 1 : 0;
}

// ============================ K1: GEMM -> ws ============================
// launch_bounds(256, 2): VGPR cap 256 -> wreg(64) + 16 in-flight float4
// stay register-resident (R7's (256,4) capped at 128 and spilled).
__global__ __launch_bounds__(256, 2) void qlstm_gemm(
    const void* __restrict__ X,
    const void* __restrict__ Wf, const void* __restrict__ Wi,
    const void* __restrict__ Wu, const void* __restrict__ Wo,
    float* __restrict__ A)
{
    __shared__ float red[4][64][32];   // 32 KiB k-partials
    __shared__ int s_isf32;

    const int tid = threadIdx.x;
    if (tid == 0) s_isf32 = sniff_f32(X);
    __syncthreads();
    const bool f32 = (s_isf32 != 0);

    const int kv = tid >> 6;        // wave = k-slice (0..3)
    const int l  = tid & 63;
    const int o  = l & 31;
    const int th = l >> 5;          // row-half
    const int g  = o >> 3, w = o & 7;
    const void* Wg = (g == 0) ? Wf : (g == 1) ? Wi : (g == 2) ? Wu : Wo;

    // persistent W slice in registers, unified f32 storage
    float4 wreg[16];
    if (f32) {
        const float4* wr = (const float4*)((const float*)Wg + w * FAN + kv * 64);
#pragma unroll
        for (int i = 0; i < 16; ++i) wreg[i] = wr[i];
    } else {
        const uint4* wr = (const uint4*)((const unsigned short*)Wg + w * FAN + kv * 64);
#pragma unroll
        for (int i = 0; i < 8; ++i) {
            uint4 wu = wr[i];
            wreg[2 * i + 0] = make_float4(lo16f(wu.x), hi16f(wu.x),
                                          lo16f(wu.y), hi16f(wu.y));
            wreg[2 * i + 1] = make_float4(lo16f(wu.z), hi16f(wu.z),
                                          lo16f(wu.w), hi16f(wu.w));
        }
    }

    const long rowbase = (long)blockIdx.x * 64;   // rows = b*256 + t
    if (f32) {
#pragma unroll 2
        for (int j = 0; j < 32; ++j) {
            const int rl = th * 32 + j;
            const long row = rowbase + rl;
            const int t = (int)(row & 255), bb = (int)(row >> 8);
            const float4* xr = (const float4*)((const float*)X
                    + ((long)t * BATCH + bb) * DIMK + kv * 64);
            float a0 = 0.f, a1 = 0.f, a2 = 0.f, a3 = 0.f;
#pragma unroll
            for (int i = 0; i < 16; ++i) {
                float4 xu = xr[i];
                a0 = fmaf(xu.x, wreg[i].x, a0);
                a1 = fmaf(xu.y, wreg[i].y, a1);
                a2 = fmaf(xu.z, wreg[i].z, a2);
                a3 = fmaf(xu.w, wreg[i].w, a3);
            }
            red[kv][rl][o] = (a0 + a1) + (a2 + a3);
        }
    } else {
#pragma unroll 2
        for (int j = 0; j < 32; ++j) {
            const int rl = th * 32 + j;
            const long row = rowbase + rl;
            const int t = (int)(row & 255), bb = (int)(row >> 8);
            const uint4* xr = (const uint4*)((const unsigned short*)X
                    + ((long)t * BATCH + bb) * DIMK + kv * 64);
            float a0 = 0.f, a1 = 0.f, a2 = 0.f, a3 = 0.f;
#pragma unroll
            for (int i = 0; i < 8; ++i) {
                uint4 xu = xr[i];
                a0 = fmaf(lo16f(xu.x), wreg[2 * i].x, a0);
                a1 = fmaf(hi16f(xu.x), wreg[2 * i].y, a1);
                a2 = fmaf(lo16f(xu.y), wreg[2 * i].z, a2);
                a3 = fmaf(hi16f(xu.y), wreg[2 * i].w, a3);
                a0 = fmaf(lo16f(xu.z), wreg[2 * i + 1].x, a0);
                a1 = fmaf(hi16f(xu.z), wreg[2 * i + 1].y, a1);
                a2 = fmaf(lo16f(xu.w), wreg[2 * i + 1].z, a2);
                a3 = fmaf(hi16f(xu.w), wreg[2 * i + 1].w, a3);
            }
            red[kv][rl][o] = (a0 + a1) + (a2 + a3);
        }
    }
    __syncthreads();
    for (int idx = tid; idx < 64 * 32; idx += 256) {
        const int rl = idx >> 5, oo = idx & 31;
        float s = red[0][rl][oo] + red[1][rl][oo]
                + red[2][rl][oo] + red[3][rl][oo];
        A[(rowbase + rl) * 32 + oo] = sane(s);
    }
}

// ========================= K2: recurrence (DPP-only) =========================
__global__ __launch_bounds__(64) void qlstm_rec(
    const void* __restrict__ X,  const void* __restrict__ hx, const void* __restrict__ cx,
    const void* __restrict__ Wf, const void* __restrict__ bf_,
    const void* __restrict__ Wi, const void* __restrict__ bi_,
    const void* __restrict__ Wu, const void* __restrict__ bu_,
    const void* __restrict__ Wo, const void* __restrict__ bo_,
    const void* __restrict__ tf, const void* __restrict__ ti,
    const void* __restrict__ tu, const void* __restrict__ to_,
    void* __restrict__ out, const float* __restrict__ A)
{
    __shared__ int s_isf32;
    const int tid = threadIdx.x;
    if (tid == 0) s_isf32 = sniff_f32(X);
    __syncthreads();
    const bool f32 = (s_isf32 != 0);

    const int p     = tid & 15;        // position in 16-lane row (one b)
    const int w     = p & 7;           // wire
    const int dup   = p >> 3;          // redundant half
    const int bglob = blockIdx.x * 4 + (tid >> 4);

    const void* Wg_[4] = { Wf, Wi, Wu, Wo };
    const void* bg_[4] = { bf_, bi_, bu_, bo_ };
    const void* tg_[4] = { tf, ti, tu, to_ };

    // XOR-permuted coefficients: Whm[g][m] pairs with h_{w^m}
    float Whm[4][8], bt[4];
#pragma unroll
    for (int g = 0; g < 4; ++g) {
#pragma unroll
        for (int m = 0; m < 8; ++m)
            Whm[g][m] = sane(ldE(Wg_[g], w * FAN + DIMK + (w ^ m), f32));
        bt[g] = sane(ldE(bg_[g], w, f32)) + sane(ldE(tg_[g], w, f32));
    }
    float h = sane(ldE(hx, bglob * 8 + w, f32));
    float c = sane(ldE(cx, bglob * 8 + w, f32));

    // inclusive cumprod over the 8-lane wire group via DPP row_shr (proven)
    auto cumprod8 = [&](float e) {
        { float v = dpp_f<0x111>(e); e = (w >= 1) ? e * v : e; }
        { float v = dpp_f<0x112>(e); e = (w >= 2) ? e * v : e; }
        { float v = dpp_f<0x114>(e); e = (w >= 4) ? e * v : e; }
        return e;
    };

    auto ldA = [&](int t, int g) {
        return A[(((long)bglob << 8) | t) * 32 + g * 8 + w];
    };

    auto STEP = [&](int t, float aF, float aI, float aU, float aO) {
        // h all-to-all within the 8-group via XOR-basis DPP (VALU pipe only):
        // hm[m] = h_{w^m}; xor1=quad_perm[1,0,3,2]=0xB1, xor2=[2,3,0,1]=0x4E,
        // xor7=row_half_mirror=0x141; others by composition.
        float h0 = h;
        float h1 = dpp_f<0xB1>(h);
        float h2 = dpp_f<0x4E>(h);
        float h3 = dpp_f<0xB1>(h2);       // xor3 = xor1∘xor2
        float h7 = dpp_f<0x141>(h);
        float h6 = dpp_f<0xB1>(h7);       // xor6 = xor1∘xor7
        float h5 = dpp_f<0x4E>(h7);       // xor5 = xor2∘xor7
        float h4 = dpp_f<0xB1>(h5);       // xor4 = xor1∘xor5

        float angF, angI, angU, angO;
        {
            float d0, d1;
            d0 = fmaf(h0, Whm[0][0], aF + bt[0]); d1 = h1 * Whm[0][1];
            d0 = fmaf(h2, Whm[0][2], d0); d1 = fmaf(h3, Whm[0][3], d1);
            d0 = fmaf(h4, Whm[0][4], d0); d1 = fmaf(h5, Whm[0][5], d1);
            d0 = fmaf(h6, Whm[0][6], d0); d1 = fmaf(h7, Whm[0][7], d1);
            angF = d0 + d1;
            d0 = fmaf(h0, Whm[1][0], aI + bt[1]); d1 = h1 * Whm[1][1];
            d0 = fmaf(h2, Whm[1][2], d0); d1 = fmaf(h3, Whm[1][3], d1);
            d0 = fmaf(h4, Whm[1][4], d0); d1 = fmaf(h5, Whm[1][5], d1);
            d0 = fmaf(h6, Whm[1][6], d0); d1 = fmaf(h7, Whm[1][7], d1);
            angI = d0 + d1;
            d0 = fmaf(h0, Whm[2][0], aU + bt[2]); d1 = h1 * Whm[2][1];
            d0 = fmaf(h2, Whm[2][2], d0); d1 = fmaf(h3, Whm[2][3], d1);
            d0 = fmaf(h4, Whm[2][4], d0); d1 = fmaf(h5, Whm[2][5], d1);
            d0 = fmaf(h6, Whm[2][6], d0); d1 = fmaf(h7, Whm[2][7], d1);
            angU = d0 + d1;
            d0 = fmaf(h0, Whm[3][0], aO + bt[3]); d1 = h1 * Whm[3][1];
            d0 = fmaf(h2, Whm[3][2], d0); d1 = fmaf(h3, Whm[3][3], d1);
            d0 = fmaf(h4, Whm[3][4], d0); d1 = fmaf(h5, Whm[3][5], d1);
            d0 = fmaf(h6, Whm[3][6], d0); d1 = fmaf(h7, Whm[3][7], d1);
            angO = d0 + d1;
        }
        float Ef = cumprod8(__cosf(angF));
        float Ei = cumprod8(__cosf(angI));
        float Eu = cumprod8(__cosf(angU));
        float Eo = cumprod8(__cosf(angO));
        float vf = sigm(Ef), vi = sigm(Ei), vu = tanh_f(Eu), vo = sigm(Eo);
        c = fmaf(vf, c, vi * vu);
        h = vo * tanh_f(c);
        if (dup == 0)
            stE(out, (long)t * 2048 + bglob * 8 + w, h, f32);
    };

    // 2-deep A prefetch into NAMED registers (static indexing only)
    float aF0 = ldA(0, 0), aI0 = ldA(0, 1), aU0 = ldA(0, 2), aO0 = ldA(0, 3);
    float aF1 = ldA(1, 0), aI1 = ldA(1, 1), aU1 = ldA(1, 2), aO1 = ldA(1, 3);
    for (int t = 0; t < S_LEN; t += 2) {
        const int tp2 = (t + 2 < S_LEN) ? t + 2 : S_LEN - 1;
        const int tp3 = (t + 3 < S_LEN) ? t + 3 : S_LEN - 1;
        float nF0 = ldA(tp2, 0), nI0 = ldA(tp2, 1);
        float nU0 = ldA(tp2, 2), nO0 = ldA(tp2, 3);
        STEP(t, aF0, aI0, aU0, aO0);
        float nF1 = ldA(tp3, 0), nI1 = ldA(tp3, 1);
        float nU1 = ldA(tp3, 2), nO1 = ldA(tp3, 3);
        STEP(t + 1, aF1, aI1, aU1, aO1);
        aF0 = nF0; aI0 = nI0; aU0 = nU0; aO0 = nO0;
        aF1 = nF1; aI1 = nI1; aU1 = nU1; aO1 = nO1;
    }
    if (dup == 0) {
        stE(out, 524288L + bglob * 8 + w, h, f32);   // hT
        stE(out, 526336L + bglob * 8 + w, c, f32);   // cT
    }
}

// ================= v6 fallback (ws too small): proven at 140us =================
__global__ __launch_bounds__(320, 1) void qlstm_fused_v6(
    const void* __restrict__ X,  const void* __restrict__ hx, const void* __restrict__ cx,
    const void* __restrict__ Wf, const void* __restrict__ bf_,
    const void* __restrict__ Wi, const void* __restrict__ bi_,
    const void* __restrict__ Wu, const void* __restrict__ bu_,
    const void* __restrict__ Wo, const void* __restrict__ bo_,
    const void* __restrict__ tf, const void* __restrict__ ti,
    const void* __restrict__ tu, const void* __restrict__ to_,
    void* __restrict__ out)
{
    __shared__ float As4[2][4][32][32];
    __shared__ int s_isf32;

    const int tid = threadIdx.x;
    const int b   = blockIdx.x;

    if (tid == 0) s_isf32 = sniff_f32(X);
    __syncthreads();
    const bool f32 = (s_isf32 != 0);

    const int wv   = tid >> 6;
    const int lane = tid & 63;
    const int kv   = wv - 1;
    const int o    = lane & 31;
    const int th   = lane >> 5;
    const int g    = o >> 3, w = o & 7;
    const void* Wg = (g == 0) ? Wf : (g == 1) ? Wi : (g == 2) ? Wu : Wo;

    float4 wreg[16];
    if (wv >= 1) {
        if (f32) {
            const float4* wr = (const float4*)((const float*)Wg + w * FAN + kv * 64);
#pragma unroll
            for (int i = 0; i < 16; ++i) wreg[i] = wr[i];
        } else {
            const uint4* wr = (const uint4*)((const unsigned short*)Wg + w * FAN + kv * 64);
#pragma unroll
            for (int i = 0; i < 8; ++i) {
                uint4 wu = wr[i];
                wreg[2 * i + 0] = make_float4(lo16f(wu.x), hi16f(wu.x),
                                              lo16f(wu.y), hi16f(wu.y));
                wreg[2 * i + 1] = make_float4(lo16f(wu.z), hi16f(wu.z),
                                              lo16f(wu.w), hi16f(wu.w));
            }
        }
    }

    auto fill = [&](int ch) {
        float (*dst)[32] = As4[ch & 1][kv];
        const int tb = ch * 32 + th * 16;
        if (f32) {
            for (int j = 0; j < 16; ++j) {
                const float4* xr = (const float4*)((const float*)X
                        + ((long)(tb + j) * BATCH + b) * DIMK + kv * 64);
                float a0 = 0.f, a1 = 0.f, a2 = 0.f, a3 = 0.f;
#pragma unroll
                for (int i = 0; i < 16; ++i) {
                    float4 xu = xr[i];
                    a0 = fmaf(xu.x, wreg[i].x, a0);
                    a1 = fmaf(xu.y, wreg[i].y, a1);
                    a2 = fmaf(xu.z, wreg[i].z, a2);
                    a3 = fmaf(xu.w, wreg[i].w, a3);
                }
                dst[th * 16 + j][o] = sane((a0 + a1) + (a2 + a3));
            }
        } else {
            for (int j = 0; j < 16; ++j) {
                const uint4* xr = (const uint4*)((const unsigned short*)X
                        + ((long)(tb + j) * BATCH + b) * DIMK + kv * 64);
                float a0 = 0.f, a1 = 0.f, a2 = 0.f, a3 = 0.f;
#pragma unroll
                for (int i = 0; i < 8; ++i) {
                    uint4 xu = xr[i];
                    a0 = fmaf(lo16f(xu.x), wreg[2 * i].x, a0);
                    a1 = fmaf(hi16f(xu.x), wreg[2 * i].y, a1);
                    a2 = fmaf(lo16f(xu.y), wreg[2 * i].z, a2);
                    a3 = fmaf(hi16f(xu.y), wreg[2 * i].w, a3);
                    a0 = fmaf(lo16f(xu.z), wreg[2 * i + 1].x, a0);
                    a1 = fmaf(hi16f(xu.z), wreg[2 * i + 1].y, a1);
                    a2 = fmaf(lo16f(xu.w), wreg[2 * i + 1].z, a2);
                    a3 = fmaf(hi16f(xu.w), wreg[2 * i + 1].w, a3);
                }
                dst[th * 16 + j][o] = sane((a0 + a1) + (a2 + a3));
            }
        }
    };

    float Wh[8];
    float bt = 0.f, h = 0.f, c = 0.f, qv = 1.f;
    int rw = 0, rg = 0;
    if (tid < 32) {
        rw = tid & 7; rg = tid >> 3;
        const void* bg = (rg == 0) ? bf_ : (rg == 1) ? bi_ : (rg == 2) ? bu_ : bo_;
        const void* tg = (rg == 0) ? tf  : (rg == 1) ? ti  : (rg == 2) ? tu  : to_;
        const int wr = rw * FAN;
#pragma unroll
        for (int j = 0; j < 8; ++j)
            Wh[j] = sane(ldE(Wg, wr + DIMK + j, f32));
        bt = sane(ldE(bg, rw, f32)) + sane(ldE(tg, rw, f32));
        h  = sane(ldE(hx, b * 8 + rw, f32));
        c  = sane(ldE(cx, b * 8 + rw, f32));
        qv = (rg == 2) ? 2.f : 1.f;
    }
    if (wv == 0) __builtin_amdgcn_s_setprio(1);

    if (wv >= 1) fill(0);
    __syncthreads();

    for (int ch = 0; ch < 8; ++ch) {
        if (wv >= 1 && ch + 1 < 8) fill(ch + 1);
        if (tid < 32) {
            const int buf = ch & 1;
            float n0 = As4[buf][0][0][tid], n1 = As4[buf][1][0][tid];
            float n2 = As4[buf][2][0][tid], n3 = As4[buf][3][0][tid];
            float a_cur = (n0 + n1) + (n2 + n3);
            for (int s = 0; s < 32; ++s) {
                const int sn = (s < 31) ? s + 1 : s;
                float m0 = As4[buf][0][sn][tid], m1 = As4[buf][1][sn][tid];
                float m2 = As4[buf][2][sn][tid], m3 = As4[buf][3][sn][tid];
                float d0 = 0.f, d1 = 0.f;
#pragma unroll
                for (int j = 0; j < 8; j += 2) {
                    d0 = fmaf(rdlane_f(h, j),     Wh[j],     d0);
                    d1 = fmaf(rdlane_f(h, j + 1), Wh[j + 1], d1);
                }
                float ang = a_cur + bt + (d0 + d1);
                float e = __cosf(ang);
                { float v = dpp_f<0x111>(e); e = (rw >= 1) ? e * v : e; }
                { float v = dpp_f<0x112>(e); e = (rw >= 2) ? e * v : e; }
                { float v = dpp_f<0x114>(e); e = (rw >= 4) ? e * v : e; }
                float ez  = __expf(qv * e);
                float val = 1.f - __fdividef(qv, ez + 1.f);
                float fg = swz_f<0x007>(val);
                float ig = swz_f<0x107>(val);
                float ug = swz_f<0x207>(val);
                float og = swz_f<0x307>(val);
                c = fmaf(fg, c, ig * ug);
                float e2 = __expf(2.f * c);
                float th2 = 1.f - __fdividef(2.f, e2 + 1.f);
                h = og * th2;
                if (rg == 0)
                    stE(out, (long)(ch * 32 + s) * 2048 + b * 8 + rw, h, f32);
                a_cur = (m0 + m1) + (m2 + m3);
            }
        }
        __syncthreads();
    }

    if (tid < 32 && rg == 0) {
        stE(out, 524288L + b * 8 + rw, h, f32);
        stE(out, 526336L + b * 8 + rw, c, f32);
    }
}

extern "C" void kernel_launch(void* const* d_in, const int* in_sizes, int n_in,
                              void* d_out, int out_size, void* d_ws, size_t ws_size,
                              hipStream_t stream) {
    if (d_ws != nullptr && ws_size >= WS_NEED) {
        qlstm_gemm<<<dim3(NROWS / 64), dim3(256), 0, stream>>>(
            d_in[0], d_in[3], d_in[5], d_in[7], d_in[9], (float*)d_ws);
        qlstm_rec<<<dim3(BATCH / 4), dim3(64), 0, stream>>>(
            d_in[0], d_in[1], d_in[2],
            d_in[3], d_in[4], d_in[5], d_in[6],
            d_in[7], d_in[8], d_in[9], d_in[10],
            d_in[11], d_in[12], d_in[13], d_in[14],
            d_out, (const float*)d_ws);
    } else {
        qlstm_fused_v6<<<dim3(BATCH), dim3(320), 0, stream>>>(
            d_in[0], d_in[1], d_in[2],
            d_in[3], d_in[4], d_in[5], d_in[6],
            d_in[7], d_in[8], d_in[9], d_in[10],
            d_in[11], d_in[12], d_in[13], d_in[14],
            d_out);
    }
}

// Round 9
// 278.992 us; speedup vs baseline: 1.1057x; 1.1010x over previous
//
#include <hip/hip_runtime.h>

// HybridQLSTMQuantum, MI355X — v9.
//   K1: 512-thr GEMM, 8 k-slices, fits 128-VGPR cap at 4 waves/SIMD.
//       Writes A repacked as [b][t][w][g] (float4 per (b,t,w)).
//   K2: recurrence; sigm/tanh of E replaced by short polynomials
//       (E = prod cos in [-1,1] guaranteed), A loaded as ONE float4/step
//       with 8-step rolling named-register prefetch. DPP-only cross-lane.
//
// qgate identity (verified analytically):
//   qgate(angles)[w] = prod_{j<=w} cos(angles[j])
//
// R8 post-mortem: LDS-swizzle -> DPP broadcast changed nothing (123us);
// critical path is trans-latency (exp/rcp chains) + possibly A-load waits.
// Poly coefficients fitted at nodes {0.25,0.5,0.75,1}; max err <= 2e-4.
// v6 single-kernel fallback retained for small ws.

#define S_LEN 256
#define BATCH 256
#define DIMK  256
#define FAN   264
#define NROWS (S_LEN * BATCH)
#define WS_NEED ((size_t)NROWS * 32 * 4)

__device__ __forceinline__ float lo16f(unsigned u) {
    union { unsigned u; float f; } v; v.u = u << 16; return v.f;
}
__device__ __forceinline__ float hi16f(unsigned u) {
    union { unsigned u; float f; } v; v.u = u & 0xffff0000u; return v.f;
}
__device__ __forceinline__ float b2f(unsigned short u) {
    union { unsigned u; float f; } v; v.u = ((unsigned)u) << 16; return v.f;
}
__device__ __forceinline__ unsigned short f2b(float f) {
    union { float f; unsigned u; } v; v.f = f;
    unsigned r = v.u + 0x7fffu + ((v.u >> 16) & 1u);  // RNE
    return (unsigned short)(r >> 16);
}
__device__ __forceinline__ float sane(float x) {
    return (__builtin_fabsf(x) < 1e30f) ? x : 0.f;   // NaN compares false -> 0
}
__device__ __forceinline__ float ldE(const void* p, int idx, bool f32) {
    return f32 ? ((const float*)p)[idx] : b2f(((const unsigned short*)p)[idx]);
}
__device__ __forceinline__ void stE(void* p, long idx, float v, bool f32) {
    if (f32) ((float*)p)[idx] = v;
    else     ((unsigned short*)p)[idx] = f2b(v);
}
__device__ __forceinline__ float tanh_f(float x) {   // exp-based (unbounded arg)
    return 1.f - __fdividef(2.f, __expf(2.f * x) + 1.f);
}
// poly sigmoid on [-1,1]: 0.5 + x*(p0 + x2*(p1 + x2*p2)), err<=1e-4
__device__ __forceinline__ float sigp(float x) {
    float x2 = x * x;
    float p = fmaf(x2, 0.0026216f, -0.0217557f);
    p = fmaf(x2, p, 0.250193f);
    return fmaf(x, p, 0.5f);
}
// poly tanh on [-1,1]: x*(1 + x2*(a + x2*(b + x2*c))), err<=2e-4
__device__ __forceinline__ float tanp(float x) {
    float x2 = x * x;
    float p = fmaf(x2, -0.028402f, 0.121713f);
    p = fmaf(x2, p, -0.331717f);
    return x * fmaf(x2, p, 1.0f);
}

// DPP: 0x00-0xFF quad_perm; 0x110|K row_shr:K; 0x141 row_half_mirror.
template<int CTRL>
__device__ __forceinline__ float dpp_f(float x) {
    int xi = __builtin_bit_cast(int, x);
    int r = __builtin_amdgcn_update_dpp(xi, xi, CTRL, 0xF, 0xF, false);
    return __builtin_bit_cast(float, r);
}
template<int IMM>
__device__ __forceinline__ float swz_f(float x) {
    return __builtin_bit_cast(float,
        __builtin_amdgcn_ds_swizzle(__builtin_bit_cast(int, x), IMM));
}
__device__ __forceinline__ float rdlane_f(float x, int l) {
    return __builtin_bit_cast(float,
        __builtin_amdgcn_readlane(__builtin_bit_cast(int, x), l));
}

__device__ __forceinline__ int sniff_f32(const void* X) {
    const unsigned short* u = (const unsigned short*)X;
    int hits = 0;
    for (int i = 0; i < 64; ++i) {
        int e = (u[2 * i] >> 7) & 0xFF;
        if (e >= 110 && e <= 135) ++hits;
    }
    return (hits < 32) ? 1 : 0;
}

// ============================ K1: GEMM -> ws ============================
// 512 thr = 8 waves; wave kv owns k in [kv*32, kv*32+32). wreg = 8 float4
// (32 VGPR) + 8 in-flight x float4 -> fits the 128-VGPR cap of (512,4):
// 4 waves/SIMD TLP hides X-load latency. A written as [b][t][w][g].
__global__ __launch_bounds__(512, 4) void qlstm_gemm(
    const void* __restrict__ X,
    const void* __restrict__ Wf, const void* __restrict__ Wi,
    const void* __restrict__ Wu, const void* __restrict__ Wo,
    float* __restrict__ A)
{
    __shared__ float red[8][64][32];   // 64 KiB k-partials

    const int tid = threadIdx.x;
    const bool f32 = sniff_f32(X) != 0;   // per-thread, uniform, cached

    const int kv = tid >> 6;        // wave = k-slice (0..7)
    const int l  = tid & 63;
    const int o  = l & 31;
    const int th = l >> 5;          // row-half
    const int g  = o >> 3, w = o & 7;
    const void* Wg = (g == 0) ? Wf : (g == 1) ? Wi : (g == 2) ? Wu : Wo;

    float4 wreg[8];
    if (f32) {
        const float4* wr = (const float4*)((const float*)Wg + w * FAN + kv * 32);
#pragma unroll
        for (int i = 0; i < 8; ++i) wreg[i] = wr[i];
    } else {
        const uint4* wr = (const uint4*)((const unsigned short*)Wg + w * FAN + kv * 32);
#pragma unroll
        for (int i = 0; i < 4; ++i) {
            uint4 wu = wr[i];
            wreg[2 * i + 0] = make_float4(lo16f(wu.x), hi16f(wu.x),
                                          lo16f(wu.y), hi16f(wu.y));
            wreg[2 * i + 1] = make_float4(lo16f(wu.z), hi16f(wu.z),
                                          lo16f(wu.w), hi16f(wu.w));
        }
    }

    const long rowbase = (long)blockIdx.x * 64;   // rows = b*256 + t
    for (int j = 0; j < 32; ++j) {
        const int rl = th * 32 + j;
        const long row = rowbase + rl;
        const int t = (int)(row & 255), bb = (int)(row >> 8);
        float a0 = 0.f, a1 = 0.f, a2 = 0.f, a3 = 0.f;
        if (f32) {
            const float4* xr = (const float4*)((const float*)X
                    + ((long)t * BATCH + bb) * DIMK + kv * 32);
#pragma unroll
            for (int i = 0; i < 8; ++i) {
                float4 xu = xr[i];
                a0 = fmaf(xu.x, wreg[i].x, a0);
                a1 = fmaf(xu.y, wreg[i].y, a1);
                a2 = fmaf(xu.z, wreg[i].z, a2);
                a3 = fmaf(xu.w, wreg[i].w, a3);
            }
        } else {
            const uint4* xr = (const uint4*)((const unsigned short*)X
                    + ((long)t * BATCH + bb) * DIMK + kv * 32);
#pragma unroll
            for (int i = 0; i < 4; ++i) {
                uint4 xu = xr[i];
                a0 = fmaf(lo16f(xu.x), wreg[2 * i].x, a0);
                a1 = fmaf(hi16f(xu.x), wreg[2 * i].y, a1);
                a2 = fmaf(lo16f(xu.y), wreg[2 * i].z, a2);
                a3 = fmaf(hi16f(xu.y), wreg[2 * i].w, a3);
                a0 = fmaf(lo16f(xu.z), wreg[2 * i + 1].x, a0);
                a1 = fmaf(hi16f(xu.z), wreg[2 * i + 1].y, a1);
                a2 = fmaf(lo16f(xu.w), wreg[2 * i + 1].z, a2);
                a3 = fmaf(hi16f(xu.w), wreg[2 * i + 1].w, a3);
            }
        }
        red[kv][rl][o] = (a0 + a1) + (a2 + a3);
    }
    __syncthreads();
    for (int idx = tid; idx < 64 * 32; idx += 512) {
        const int rl = idx >> 5, oo = idx & 31;
        float s = 0.f;
#pragma unroll
        for (int k = 0; k < 8; ++k) s += red[k][rl][oo];
        // repack: column = w*4 + g  (K2 reads one float4 per (b,t,w))
        A[(rowbase + rl) * 32 + (oo & 7) * 4 + (oo >> 3)] = sane(s);
    }
}

// ========================= K2: recurrence =========================
// 64 blocks x 64 thr; wave = 4 b-rows x 16 lanes (w x dup).
// Per step: ONE float4 A-load (8-step rolling prefetch), DPP h all-to-all,
// DPP cumprod, POLY gate nonlinearities (E in [-1,1]), exp-tanh for c only.
__global__ __launch_bounds__(64) void qlstm_rec(
    const void* __restrict__ X,  const void* __restrict__ hx, const void* __restrict__ cx,
    const void* __restrict__ Wf, const void* __restrict__ bf_,
    const void* __restrict__ Wi, const void* __restrict__ bi_,
    const void* __restrict__ Wu, const void* __restrict__ bu_,
    const void* __restrict__ Wo, const void* __restrict__ bo_,
    const void* __restrict__ tf, const void* __restrict__ ti,
    const void* __restrict__ tu, const void* __restrict__ to_,
    void* __restrict__ out, const float* __restrict__ A)
{
    const int tid = threadIdx.x;
    const bool f32 = sniff_f32(X) != 0;

    const int p     = tid & 15;        // position in 16-lane row (one b)
    const int w     = p & 7;           // wire
    const int dup   = p >> 3;          // redundant half
    const int bglob = blockIdx.x * 4 + (tid >> 4);

    const void* Wg_[4] = { Wf, Wi, Wu, Wo };
    const void* bg_[4] = { bf_, bi_, bu_, bo_ };
    const void* tg_[4] = { tf, ti, tu, to_ };

    // XOR-permuted coefficients: Whm[g][m] pairs with h_{w^m}
    float Whm[4][8], bt[4];
#pragma unroll
    for (int g = 0; g < 4; ++g) {
#pragma unroll
        for (int m = 0; m < 8; ++m)
            Whm[g][m] = sane(ldE(Wg_[g], w * FAN + DIMK + (w ^ m), f32));
        bt[g] = sane(ldE(bg_[g], w, f32)) + sane(ldE(tg_[g], w, f32));
    }
    float h = sane(ldE(hx, bglob * 8 + w, f32));
    float c = sane(ldE(cx, bglob * 8 + w, f32));

    auto cumprod8 = [&](float e) {
        { float v = dpp_f<0x111>(e); e = (w >= 1) ? e * v : e; }
        { float v = dpp_f<0x112>(e); e = (w >= 2) ? e * v : e; }
        { float v = dpp_f<0x114>(e); e = (w >= 4) ? e * v : e; }
        return e;
    };

    const float4* A4 = (const float4*)A;
    auto ld4 = [&](int t) {
        return A4[((((long)bglob << 8) | t) << 3) + w];   // (b,t,w) quad
    };

    auto STEP = [&](int t, float4 a) {
        // h all-to-all via XOR-basis DPP (verified R8, bit-identical output)
        float h0 = h;
        float h1 = dpp_f<0xB1>(h);
        float h2 = dpp_f<0x4E>(h);
        float h3 = dpp_f<0xB1>(h2);       // xor3
        float h7 = dpp_f<0x141>(h);
        float h6 = dpp_f<0xB1>(h7);       // xor6
        float h5 = dpp_f<0x4E>(h7);       // xor5
        float h4 = dpp_f<0xB1>(h5);       // xor4

        float angF, angI, angU, angO;
        {
            float d0, d1;
            d0 = fmaf(h0, Whm[0][0], a.x + bt[0]); d1 = h1 * Whm[0][1];
            d0 = fmaf(h2, Whm[0][2], d0); d1 = fmaf(h3, Whm[0][3], d1);
            d0 = fmaf(h4, Whm[0][4], d0); d1 = fmaf(h5, Whm[0][5], d1);
            d0 = fmaf(h6, Whm[0][6], d0); d1 = fmaf(h7, Whm[0][7], d1);
            angF = d0 + d1;
            d0 = fmaf(h0, Whm[1][0], a.y + bt[1]); d1 = h1 * Whm[1][1];
            d0 = fmaf(h2, Whm[1][2], d0); d1 = fmaf(h3, Whm[1][3], d1);
            d0 = fmaf(h4, Whm[1][4], d0); d1 = fmaf(h5, Whm[1][5], d1);
            d0 = fmaf(h6, Whm[1][6], d0); d1 = fmaf(h7, Whm[1][7], d1);
            angI = d0 + d1;
            d0 = fmaf(h0, Whm[2][0], a.z + bt[2]); d1 = h1 * Whm[2][1];
            d0 = fmaf(h2, Whm[2][2], d0); d1 = fmaf(h3, Whm[2][3], d1);
            d0 = fmaf(h4, Whm[2][4], d0); d1 = fmaf(h5, Whm[2][5], d1);
            d0 = fmaf(h6, Whm[2][6], d0); d1 = fmaf(h7, Whm[2][7], d1);
            angU = d0 + d1;
            d0 = fmaf(h0, Whm[3][0], a.w + bt[3]); d1 = h1 * Whm[3][1];
            d0 = fmaf(h2, Whm[3][2], d0); d1 = fmaf(h3, Whm[3][3], d1);
            d0 = fmaf(h4, Whm[3][4], d0); d1 = fmaf(h5, Whm[3][5], d1);
            d0 = fmaf(h6, Whm[3][6], d0); d1 = fmaf(h7, Whm[3][7], d1);
            angO = d0 + d1;
        }
        float Ef = cumprod8(__cosf(angF));
        float Ei = cumprod8(__cosf(angI));
        float Eu = cumprod8(__cosf(angU));
        float Eo = cumprod8(__cosf(angO));
        // POLY nonlinearities (E guaranteed in [-1,1])
        float vf = sigp(Ef), vi = sigp(Ei), vu = tanp(Eu), vo = sigp(Eo);
        c = fmaf(vf, c, vi * vu);
        h = vo * tanh_f(c);
        if (dup == 0)
            stE(out, (long)t * 2048 + bglob * 8 + w, h, f32);
    };

    // 8-step rolling prefetch, all named registers
    float4 a0 = ld4(0), a1 = ld4(1), a2 = ld4(2), a3 = ld4(3);
    float4 a4 = ld4(4), a5 = ld4(5), a6 = ld4(6), a7 = ld4(7);
    for (int t = 0; t < S_LEN; t += 8) {
        const int tn = t + 8;
        const int L = S_LEN - 1;
        float4 n0 = ld4(tn     < S_LEN ? tn     : L); STEP(t,     a0);
        float4 n1 = ld4(tn + 1 < S_LEN ? tn + 1 : L); STEP(t + 1, a1);
        float4 n2 = ld4(tn + 2 < S_LEN ? tn + 2 : L); STEP(t + 2, a2);
        float4 n3 = ld4(tn + 3 < S_LEN ? tn + 3 : L); STEP(t + 3, a3);
        float4 n4 = ld4(tn + 4 < S_LEN ? tn + 4 : L); STEP(t + 4, a4);
        float4 n5 = ld4(tn + 5 < S_LEN ? tn + 5 : L); STEP(t + 5, a5);
        float4 n6 = ld4(tn + 6 < S_LEN ? tn + 6 : L); STEP(t + 6, a6);
        float4 n7 = ld4(tn + 7 < S_LEN ? tn + 7 : L); STEP(t + 7, a7);
        a0 = n0; a1 = n1; a2 = n2; a3 = n3;
        a4 = n4; a5 = n5; a6 = n6; a7 = n7;
    }
    if (dup == 0) {
        stE(out, 524288L + bglob * 8 + w, h, f32);   // hT
        stE(out, 526336L + bglob * 8 + w, c, f32);   // cT
    }
}

// ================= v6 fallback (ws too small): proven at 140us =================
__global__ __launch_bounds__(320, 1) void qlstm_fused_v6(
    const void* __restrict__ X,  const void* __restrict__ hx, const void* __restrict__ cx,
    const void* __restrict__ Wf, const void* __restrict__ bf_,
    const void* __restrict__ Wi, const void* __restrict__ bi_,
    const void* __restrict__ Wu, const void* __restrict__ bu_,
    const void* __restrict__ Wo, const void* __restrict__ bo_,
    const void* __restrict__ tf, const void* __restrict__ ti,
    const void* __restrict__ tu, const void* __restrict__ to_,
    void* __restrict__ out)
{
    __shared__ float As4[2][4][32][32];

    const int tid = threadIdx.x;
    const int b   = blockIdx.x;
    const bool f32 = sniff_f32(X) != 0;

    const int wv   = tid >> 6;
    const int lane = tid & 63;
    const int kv   = wv - 1;
    const int o    = lane & 31;
    const int th   = lane >> 5;
    const int g    = o >> 3, w = o & 7;
    const void* Wg = (g == 0) ? Wf : (g == 1) ? Wi : (g == 2) ? Wu : Wo;

    float4 wreg[16];
    if (wv >= 1) {
        if (f32) {
            const float4* wr = (const float4*)((const float*)Wg + w * FAN + kv * 64);
#pragma unroll
            for (int i = 0; i < 16; ++i) wreg[i] = wr[i];
        } else {
            const uint4* wr = (const uint4*)((const unsigned short*)Wg + w * FAN + kv * 64);
#pragma unroll
            for (int i = 0; i < 8; ++i) {
                uint4 wu = wr[i];
                wreg[2 * i + 0] = make_float4(lo16f(wu.x), hi16f(wu.x),
                                              lo16f(wu.y), hi16f(wu.y));
                wreg[2 * i + 1] = make_float4(lo16f(wu.z), hi16f(wu.z),
                                              lo16f(wu.w), hi16f(wu.w));
            }
        }
    }

    auto fill = [&](int ch) {
        float (*dst)[32] = As4[ch & 1][kv];
        const int tb = ch * 32 + th * 16;
        if (f32) {
            for (int j = 0; j < 16; ++j) {
                const float4* xr = (const float4*)((const float*)X
                        + ((long)(tb + j) * BATCH + b) * DIMK + kv * 64);
                float a0 = 0.f, a1 = 0.f, a2 = 0.f, a3 = 0.f;
#pragma unroll
                for (int i = 0; i < 16; ++i) {
                    float4 xu = xr[i];
                    a0 = fmaf(xu.x, wreg[i].x, a0);
                    a1 = fmaf(xu.y, wreg[i].y, a1);
                    a2 = fmaf(xu.z, wreg[i].z, a2);
                    a3 = fmaf(xu.w, wreg[i].w, a3);
                }
                dst[th * 16 + j][o] = sane((a0 + a1) + (a2 + a3));
            }
        } else {
            for (int j = 0; j < 16; ++j) {
                const uint4* xr = (const uint4*)((const unsigned short*)X
                        + ((long)(tb + j) * BATCH + b) * DIMK + kv * 64);
                float a0 = 0.f, a1 = 0.f, a2 = 0.f, a3 = 0.f;
#pragma unroll
                for (int i = 0; i < 8; ++i) {
                    uint4 xu = xr[i];
                    a0 = fmaf(lo16f(xu.x), wreg[2 * i].x, a0);
                    a1 = fmaf(hi16f(xu.x), wreg[2 * i].y, a1);
                    a2 = fmaf(lo16f(xu.y), wreg[2 * i].z, a2);
                    a3 = fmaf(hi16f(xu.y), wreg[2 * i].w, a3);
                    a0 = fmaf(lo16f(xu.z), wreg[2 * i + 1].x, a0);
                    a1 = fmaf(hi16f(xu.z), wreg[2 * i + 1].y, a1);
                    a2 = fmaf(lo16f(xu.w), wreg[2 * i + 1].z, a2);
                    a3 = fmaf(hi16f(xu.w), wreg[2 * i + 1].w, a3);
                }
                dst[th * 16 + j][o] = sane((a0 + a1) + (a2 + a3));
            }
        }
    };

    float Wh[8];
    float bt = 0.f, h = 0.f, c = 0.f, qv = 1.f;
    int rw = 0, rg = 0;
    if (tid < 32) {
        rw = tid & 7; rg = tid >> 3;
        const void* bg = (rg == 0) ? bf_ : (rg == 1) ? bi_ : (rg == 2) ? bu_ : bo_;
        const void* tg = (rg == 0) ? tf  : (rg == 1) ? ti  : (rg == 2) ? tu  : to_;
        const int wr = rw * FAN;
#pragma unroll
        for (int j = 0; j < 8; ++j)
            Wh[j] = sane(ldE(Wg, wr + DIMK + j, f32));
        bt = sane(ldE(bg, rw, f32)) + sane(ldE(tg, rw, f32));
        h  = sane(ldE(hx, b * 8 + rw, f32));
        c  = sane(ldE(cx, b * 8 + rw, f32));
        qv = (rg == 2) ? 2.f : 1.f;
    }
    if (wv == 0) __builtin_amdgcn_s_setprio(1);

    if (wv >= 1) fill(0);
    __syncthreads();

    for (int ch = 0; ch < 8; ++ch) {
        if (wv >= 1 && ch + 1 < 8) fill(ch + 1);
        if (tid < 32) {
            const int buf = ch & 1;
            float n0 = As4[buf][0][0][tid], n1 = As4[buf][1][0][tid];
            float n2 = As4[buf][2][0][tid], n3 = As4[buf][3][0][tid];
            float a_cur = (n0 + n1) + (n2 + n3);
            for (int s = 0; s < 32; ++s) {
                const int sn = (s < 31) ? s + 1 : s;
                float m0 = As4[buf][0][sn][tid], m1 = As4[buf][1][sn][tid];
                float m2 = As4[buf][2][sn][tid], m3 = As4[buf][3][sn][tid];
                float d0 = 0.f, d1 = 0.f;
#pragma unroll
                for (int j = 0; j < 8; j += 2) {
                    d0 = fmaf(rdlane_f(h, j),     Wh[j],     d0);
                    d1 = fmaf(rdlane_f(h, j + 1), Wh[j + 1], d1);
                }
                float ang = a_cur + bt + (d0 + d1);
                float e = __cosf(ang);
                { float v = dpp_f<0x111>(e); e = (rw >= 1) ? e * v : e; }
                { float v = dpp_f<0x112>(e); e = (rw >= 2) ? e * v : e; }
                { float v = dpp_f<0x114>(e); e = (rw >= 4) ? e * v : e; }
                float ez  = __expf(qv * e);
                float val = 1.f - __fdividef(qv, ez + 1.f);
                float fg = swz_f<0x007>(val);
                float ig = swz_f<0x107>(val);
                float ug = swz_f<0x207>(val);
                float og = swz_f<0x307>(val);
                c = fmaf(fg, c, ig * ug);
                float e2 = __expf(2.f * c);
                float th2 = 1.f - __fdividef(2.f, e2 + 1.f);
                h = og * th2;
                if (rg == 0)
                    stE(out, (long)(ch * 32 + s) * 2048 + b * 8 + rw, h, f32);
                a_cur = (m0 + m1) + (m2 + m3);
            }
        }
        __syncthreads();
    }

    if (tid < 32 && rg == 0) {
        stE(out, 524288L + b * 8 + rw, h, f32);
        stE(out, 526336L + b * 8 + rw, c, f32);
    }
}

extern "C" void kernel_launch(void* const* d_in, const int* in_sizes, int n_in,
                              void* d_out, int out_size, void* d_ws, size_t ws_size,
                              hipStream_t stream) {
    if (d_ws != nullptr && ws_size >= WS_NEED) {
        qlstm_gemm<<<dim3(NROWS / 64), dim3(512), 0, stream>>>(
            d_in[0], d_in[3], d_in[5], d_in[7], d_in[9], (float*)d_ws);
        qlstm_rec<<<dim3(BATCH / 4), dim3(64), 0, stream>>>(
            d_in[0], d_in[1], d_in[2],
            d_in[3], d_in[4], d_in[5], d_in[6],
            d_in[7], d_in[8], d_in[9], d_in[10],
            d_in[11], d_in[12], d_in[13], d_in[14],
            d_out, (const float*)d_ws);
    } else {
        qlstm_fused_v6<<<dim3(BATCH), dim3(320), 0, stream>>>(
            d_in[0], d_in[1], d_in[2],
            d_in[3], d_in[4], d_in[5], d_in[6],
            d_in[7], d_in[8], d_in[9], d_in[10],
            d_in[11], d_in[12], d_in[13], d_in[14],
            d_out);
    }
}